// Round 2
// baseline (1152.795 us; speedup 1.0000x reference)
//
#include <hip/hip_runtime.h>
#include <type_traits>

#define H_    32
#define HKV_  8
#define HD_   128
#define D_    4096   // H*HD
#define KVD_  1024   // HKV*HD

typedef __attribute__((ext_vector_type(8))) short s8v;   // 8 x bf16 bits (4 VGPRs)
typedef __attribute__((ext_vector_type(4))) short s4v;
typedef __attribute__((ext_vector_type(4))) float f4v;

__device__ __forceinline__ float b2f(unsigned short u) {
  union { unsigned int i; float f; } v; v.i = ((unsigned int)u) << 16; return v.f;
}
__device__ __forceinline__ unsigned short f2b(float f) {
  unsigned int u = __float_as_uint(f);
  u += 0x7fffu + ((u >> 16) & 1u);          // round-to-nearest-even
  return (unsigned short)(u >> 16);
}

// ---------------------------------------------------------------------------
// C[M x N] = A[M x K] @ W[K x N] + bias.  A: fp32 or bf16-bits; W,bias: fp32;
// C: fp32 or bf16-bits. bf16 MFMA internally, fp32 accumulate.
// 64x64 block tile, 4 waves, 16x16x32 MFMA.
// ---------------------------------------------------------------------------
template <typename AT, typename OT>
__global__ __launch_bounds__(256) void gemm_bias(
    const AT* __restrict__ A, const float* __restrict__ W,
    const float* __restrict__ bias, OT* __restrict__ C,
    int M, int N, int K)
{
  __shared__ __align__(16) unsigned short As[64][40];   // 64 rows x 32 k (+8 pad)
  __shared__ __align__(16) unsigned short Bs[32][68];   // 32 k x 64 n (+4 pad)

  const int tid  = threadIdx.x;
  const int wave = tid >> 6;
  const int lane = tid & 63;
  const int l16  = lane & 15;
  const int quad = lane >> 4;
  const int row0 = blockIdx.y * 64;
  const int col0 = blockIdx.x * 64;

  f4v acc[4] = {};

  const int ar = tid >> 2;            // 0..63
  const int ac = (tid & 3) << 3;      // 0,8,16,24
  const int bk = tid >> 3;            // 0..31
  const int bn = (tid & 7) << 3;      // 0..56
  const AT*    Aptr = A + (size_t)(row0 + ar) * K + ac;
  const float* Wptr = W + (size_t)bk * N + col0 + bn;

  for (int k0 = 0; k0 < K; k0 += 32) {
    __syncthreads();                         // protect LDS from prior-iter reads
    if constexpr (std::is_same_v<AT, float>) {
      float4 a0 = *(const float4*)(Aptr);
      float4 a1 = *(const float4*)(Aptr + 4);
      s8v av;
      av[0] = (short)f2b(a0.x); av[1] = (short)f2b(a0.y);
      av[2] = (short)f2b(a0.z); av[3] = (short)f2b(a0.w);
      av[4] = (short)f2b(a1.x); av[5] = (short)f2b(a1.y);
      av[6] = (short)f2b(a1.z); av[7] = (short)f2b(a1.w);
      *(s8v*)&As[ar][ac] = av;
    } else {
      *(s8v*)&As[ar][ac] = *(const s8v*)(Aptr);
    }
    Aptr += 32;
    {
      float4 w0 = *(const float4*)(Wptr);
      float4 w1 = *(const float4*)(Wptr + 4);
      s4v b0, b1;
      b0[0] = (short)f2b(w0.x); b0[1] = (short)f2b(w0.y);
      b0[2] = (short)f2b(w0.z); b0[3] = (short)f2b(w0.w);
      b1[0] = (short)f2b(w1.x); b1[1] = (short)f2b(w1.y);
      b1[2] = (short)f2b(w1.z); b1[3] = (short)f2b(w1.w);
      *(s4v*)&Bs[bk][bn]     = b0;           // 136B row stride -> 8B-aligned stores
      *(s4v*)&Bs[bk][bn + 4] = b1;
    }
    Wptr += (size_t)32 * N;
    __syncthreads();

    s8v a = *(const s8v*)&As[wave * 16 + l16][quad * 8];
#pragma unroll
    for (int nt = 0; nt < 4; ++nt) {
      s8v b;
#pragma unroll
      for (int j = 0; j < 8; ++j) b[j] = (short)Bs[quad * 8 + j][nt * 16 + l16];
      acc[nt] = __builtin_amdgcn_mfma_f32_16x16x32_bf16(a, b, acc[nt], 0, 0, 0);
    }
  }

#pragma unroll
  for (int nt = 0; nt < 4; ++nt) {
    int col = col0 + nt * 16 + l16;
    float bv = bias[col];
#pragma unroll
    for (int r = 0; r < 4; ++r) {
      int row = row0 + wave * 16 + quad * 4 + r;   // C/D layout: row = quad*4+reg
      float o = acc[nt][r] + bv;
      if constexpr (std::is_same_v<OT, float>) C[(size_t)row * N + col] = o;
      else                                     C[(size_t)row * N + col] = f2b(o);
    }
  }
}

// ---------------------------------------------------------------------------
// RoPE (rotate-half) on q [T,32,128] and k [T,8,128] (bf16 bits) in place.
// ---------------------------------------------------------------------------
__global__ void rope_kernel(unsigned short* __restrict__ q,
                            unsigned short* __restrict__ k,
                            const int* __restrict__ pos, int T)
{
  const int t  = blockIdx.x;
  const int hh = blockIdx.y;              // 0..39
  const int d  = threadIdx.x;             // 0..63
  unsigned short* p = (hh < H_) ? q + ((size_t)t * D_ + hh * HD_)
                                : k + ((size_t)t * KVD_ + (hh - H_) * HD_);
  float pv   = (float)pos[t];
  float inv  = powf(1.0e6f, -(float)d * (1.0f / 64.0f));
  float fr   = pv * inv;
  float s, c;
  sincosf(fr, &s, &c);
  float x1 = b2f(p[d]), x2 = b2f(p[d + 64]);
  p[d]      = f2b(x1 * c - x2 * s);
  p[d + 64] = f2b(x2 * c + x1 * s);
}

// ---------------------------------------------------------------------------
// Block-sparse flash attention (bf16 in/out). One block per (head h, q-block).
// kv block kb active iff kb<=qb && (qb-kb<16 || (kb+h+1)%8==0).
// ---------------------------------------------------------------------------
__global__ __launch_bounds__(256) void attn_sparse(
    const unsigned short* __restrict__ Q, const unsigned short* __restrict__ K,
    const unsigned short* __restrict__ V, unsigned short* __restrict__ O, int T)
{
  __shared__ __align__(16) unsigned short Ks[64][136];   // [k][d], pad 8
  __shared__ __align__(16) unsigned short Vt[128][72];   // [d][k], pad 8
  __shared__ __align__(16) unsigned short Ps[4][16][72]; // per-wave P round-trip

  const int h   = blockIdx.x;
  const int qb  = blockIdx.y;
  const int hkv = h >> 2;                 // GQA: repeat each kv head 4x
  const int tid  = threadIdx.x;
  const int wave = tid >> 6;
  const int lane = tid & 63;
  const int l16  = lane & 15;
  const int quad = lane >> 4;

  // Q A-fragments for this wave's 16 rows (4 k-steps over HD=128)
  const int qrow = qb * 64 + wave * 16 + l16;
  s8v qf[4];
#pragma unroll
  for (int s = 0; s < 4; ++s)
    qf[s] = *(const s8v*)(Q + (size_t)qrow * D_ + h * HD_ + s * 32 + quad * 8);

  float mrow[4] = {-1e30f, -1e30f, -1e30f, -1e30f};
  float lrow[4] = {0.f, 0.f, 0.f, 0.f};
  f4v oacc[8] = {};
  const int srow_base = qb * 64 + wave * 16 + quad * 4;   // C-layout row base

  for (int kb = 0; kb <= qb; ++kb) {
    if (!((qb - kb < 16) || (((kb + h + 1) & 7) == 0))) continue;

    __syncthreads();
#pragma unroll
    for (int i = 0; i < 4; ++i) {
      int seg = tid + 256 * i;
      int kr  = seg >> 4;                 // 0..63
      int c   = (seg & 15) << 3;          // 0..120
      const size_t goff = (size_t)(kb * 64 + kr) * KVD_ + hkv * HD_ + c;
      *(s8v*)&Ks[kr][c] = *(const s8v*)(K + goff);
      s8v vv = *(const s8v*)(V + goff);
#pragma unroll
      for (int u = 0; u < 8; ++u) Vt[c + u][kr] = (unsigned short)vv[u];
    }
    __syncthreads();

    // S = Q K^T  (4 n-subtiles of 16 keys, 4 k-steps over d)
    f4v sacc[4] = {};
#pragma unroll
    for (int kt = 0; kt < 4; ++kt) {
#pragma unroll
      for (int s = 0; s < 4; ++s) {
        s8v b = *(const s8v*)&Ks[kt * 16 + l16][s * 32 + quad * 8];
        sacc[kt] = __builtin_amdgcn_mfma_f32_16x16x32_bf16(qf[s], b, sacc[kt], 0, 0, 0);
      }
    }

    // scale + causal mask + online softmax
    float p[4][4], rmax[4];
#pragma unroll
    for (int r = 0; r < 4; ++r) {
      float mx = -1e30f;
#pragma unroll
      for (int kt = 0; kt < 4; ++kt) {
        float sc = sacc[kt][r] * 0.08838834764831845f;
        int kcol = kb * 64 + kt * 16 + l16;
        if (kcol > srow_base + r) sc = -1e30f;   // per-element causal
        p[r][kt] = sc;
        mx = fmaxf(mx, sc);
      }
#pragma unroll
      for (int off = 1; off < 16; off <<= 1)
        mx = fmaxf(mx, __shfl_xor(mx, off));
      rmax[r] = mx;
    }

    float alpha[4];
#pragma unroll
    for (int r = 0; r < 4; ++r) {
      float newm = fmaxf(mrow[r], rmax[r]);
      alpha[r] = __expf(mrow[r] - newm);
      mrow[r] = newm;
      float rs = 0.f;
#pragma unroll
      for (int kt = 0; kt < 4; ++kt) {
        unsigned short pb = f2b(__expf(p[r][kt] - newm));
        Ps[wave][quad * 4 + r][kt * 16 + l16] = pb;   // C-layout -> LDS
        rs += b2f(pb);                                // sum what we actually use
      }
#pragma unroll
      for (int off = 1; off < 16; off <<= 1)
        rs += __shfl_xor(rs, off);
      lrow[r] = lrow[r] * alpha[r] + rs;
    }
#pragma unroll
    for (int dt = 0; dt < 8; ++dt) {
#pragma unroll
      for (int r = 0; r < 4; ++r) oacc[dt][r] *= alpha[r];
    }

    __syncthreads();   // P writes ordered before A-layout reads

    // O += P @ V   (2 k-steps over 64 keys, 8 d-subtiles)
#pragma unroll
    for (int s2 = 0; s2 < 2; ++s2) {
      s8v af = *(const s8v*)&Ps[wave][l16][s2 * 32 + quad * 8];
#pragma unroll
      for (int dt = 0; dt < 8; ++dt) {
        s8v vf = *(const s8v*)&Vt[dt * 16 + l16][s2 * 32 + quad * 8];
        oacc[dt] = __builtin_amdgcn_mfma_f32_16x16x32_bf16(af, vf, oacc[dt], 0, 0, 0);
      }
    }
  }

  // epilogue: normalize and store [T, H*HD] (bf16 bits)
#pragma unroll
  for (int r = 0; r < 4; ++r) {
    float inv = 1.0f / lrow[r];
    size_t rowoff = (size_t)(srow_base + r) * D_ + h * HD_;
#pragma unroll
    for (int dt = 0; dt < 8; ++dt)
      O[rowoff + dt * 16 + l16] = f2b(oacc[dt][r] * inv);
  }
}

// ---------------------------------------------------------------------------
extern "C" void kernel_launch(void* const* d_in, const int* in_sizes, int n_in,
                              void* d_out, int out_size, void* d_ws, size_t ws_size,
                              hipStream_t stream)
{
  const float* hs  = (const float*)d_in[0];
  const int*   pos = (const int*)d_in[1];
  const float* Wq  = (const float*)d_in[2];
  const float* bq  = (const float*)d_in[3];
  const float* Wk  = (const float*)d_in[4];
  const float* bk  = (const float*)d_in[5];
  const float* Wv  = (const float*)d_in[6];
  const float* bv  = (const float*)d_in[7];
  const float* Wo  = (const float*)d_in[8];
  const float* bo  = (const float*)d_in[9];
  float* out = (float*)d_out;

  const int T = in_sizes[1];   // positions count = 2048

  // workspace (bf16 bits): q[T*4096] k[T*1024] v[T*1024] attn[T*4096] ~ 42 MB
  unsigned short* qbuf = (unsigned short*)d_ws;
  unsigned short* kbuf = qbuf + (size_t)T * D_;
  unsigned short* vbuf = kbuf + (size_t)T * KVD_;
  unsigned short* abuf = vbuf + (size_t)T * KVD_;

  dim3 blk(256);
  gemm_bias<float, unsigned short>
      <<<dim3(D_ / 64,   T / 64), blk, 0, stream>>>(hs, Wq, bq, qbuf, T, D_,   D_);
  gemm_bias<float, unsigned short>
      <<<dim3(KVD_ / 64, T / 64), blk, 0, stream>>>(hs, Wk, bk, kbuf, T, KVD_, D_);
  gemm_bias<float, unsigned short>
      <<<dim3(KVD_ / 64, T / 64), blk, 0, stream>>>(hs, Wv, bv, vbuf, T, KVD_, D_);
  rope_kernel<<<dim3(T, H_ + HKV_), dim3(64), 0, stream>>>(qbuf, kbuf, pos, T);
  attn_sparse<<<dim3(H_, T / 64), blk, 0, stream>>>(qbuf, kbuf, vbuf, abuf, T);
  gemm_bias<unsigned short, float>
      <<<dim3(D_ / 64,   T / 64), blk, 0, stream>>>(abuf, Wo, bo, out, T, D_,   D_);
}

// Round 3
// 806.882 us; speedup vs baseline: 1.4287x; 1.4287x over previous
//
#include <hip/hip_runtime.h>
#include <type_traits>

#define H_    32
#define HKV_  8
#define HD_   128
#define D_    4096   // H*HD
#define KVD_  1024   // HKV*HD

typedef __attribute__((ext_vector_type(8))) short s8v;   // 8 x bf16 bits (4 VGPRs)
typedef __attribute__((ext_vector_type(4))) short s4v;
typedef __attribute__((ext_vector_type(4))) float f4v;

__device__ __forceinline__ float b2f(unsigned short u) {
  union { unsigned int i; float f; } v; v.i = ((unsigned int)u) << 16; return v.f;
}
__device__ __forceinline__ unsigned short f2b(float f) {
  unsigned int u = __float_as_uint(f);
  u += 0x7fffu + ((u >> 16) & 1u);          // round-to-nearest-even
  return (unsigned short)(u >> 16);
}

// async global->LDS, 16B per lane; LDS dest = wave-uniform base + lane*16
__device__ __forceinline__ void gload16(const unsigned short* g, unsigned short* l) {
  __builtin_amdgcn_global_load_lds((const __attribute__((address_space(1))) void*)g,
                                   (__attribute__((address_space(3))) void*)l, 16, 0, 0);
}

// ---------------------------------------------------------------------------
// fp32 -> bf16 flat convert (8 elems/thread)
// ---------------------------------------------------------------------------
__global__ void cvt_bf16(const float* __restrict__ x, unsigned short* __restrict__ y,
                         int n8)
{
  int i = blockIdx.x * blockDim.x + threadIdx.x;
  if (i >= n8) return;
  const float4* xp = (const float4*)x + (size_t)i * 2;
  float4 a = xp[0], b = xp[1];
  s8v v;
  v[0] = (short)f2b(a.x); v[1] = (short)f2b(a.y);
  v[2] = (short)f2b(a.z); v[3] = (short)f2b(a.w);
  v[4] = (short)f2b(b.x); v[5] = (short)f2b(b.y);
  v[6] = (short)f2b(b.z); v[7] = (short)f2b(b.w);
  *(s8v*)(y + (size_t)i * 8) = v;
}

// ---------------------------------------------------------------------------
// W [K][N] fp32 -> Wt [N][K] bf16, 64x64 LDS-tiled transpose+convert
// ---------------------------------------------------------------------------
__global__ __launch_bounds__(256) void cvt_transpose(
    const float* __restrict__ W, unsigned short* __restrict__ Wt, int K, int N)
{
  __shared__ unsigned short tile[64][72];   // [n][k], pad -> 144B row (16B aligned)
  const int k0 = blockIdx.y * 64, n0 = blockIdx.x * 64;
  const int tid = threadIdx.x;
#pragma unroll
  for (int it = 0; it < 4; ++it) {
    int idx = tid + it * 256;            // 0..1023
    int r = idx >> 4;                    // k in tile, 0..63
    int c = (idx & 15) << 2;             // n in tile, 0..60
    float4 w = *(const float4*)(W + (size_t)(k0 + r) * N + n0 + c);
    tile[c + 0][r] = f2b(w.x); tile[c + 1][r] = f2b(w.y);
    tile[c + 2][r] = f2b(w.z); tile[c + 3][r] = f2b(w.w);
  }
  __syncthreads();
#pragma unroll
  for (int it = 0; it < 2; ++it) {
    int idx = tid + it * 256;            // 0..511
    int n = idx >> 3;                    // 0..63
    int kk = (idx & 7) << 3;             // 0..56
    *(s8v*)(Wt + (size_t)(n0 + n) * K + k0 + kk) = *(const s8v*)&tile[n][kk];
  }
}

// ---------------------------------------------------------------------------
// m97-style GEMM: C[M][N] = A[M][K] @ Bt[N][K]^T + bias.  A,Bt bf16; bias fp32.
// 128x128 tile, BK=32, 256 threads (4 waves, each 64x64 = 4x4 MFMA accs).
// global_load_lds width-16 staging; ds_read_b128 fragments (no LDS padding).
// ---------------------------------------------------------------------------
template <typename OT>
__global__ __launch_bounds__(256) void gemm_bt(
    const unsigned short* __restrict__ A, const unsigned short* __restrict__ Bt,
    const float* __restrict__ bias, OT* __restrict__ C, int M, int N, int K)
{
  __shared__ __align__(16) unsigned short As[128 * 32];   // [row][k], 8 KB
  __shared__ __align__(16) unsigned short Bs[128 * 32];   // [col][k], 8 KB

  const int tid  = threadIdx.x;
  const int wave = tid >> 6;
  const int lane = tid & 63;
  const int l16  = lane & 15;
  const int quad = lane >> 4;
  const int row0 = blockIdx.y * 128;
  const int col0 = blockIdx.x * 128;
  const int wr   = wave >> 1, wc = wave & 1;

  // staging: 8 KB per operand = 8 wave-instructions; each wave does 2 per operand
  const int srow = lane >> 2;            // 0..15
  const int skk  = (lane & 3) << 3;      // 0,8,16,24
  const unsigned short* Ap = A  + (size_t)(row0 + wave * 32 + srow) * K + skk;
  const unsigned short* Bp = Bt + (size_t)(col0 + wave * 32 + srow) * K + skk;
  unsigned short* AsW = As + wave * 1024;   // (wave*2+t)*512 elems, t in {0,1}
  unsigned short* BsW = Bs + wave * 1024;

  f4v acc[4][4] = {};

  for (int k0 = 0; k0 < K; k0 += 32) {
    __syncthreads();                     // prior-iter LDS reads done
    gload16(Ap,           AsW);
    gload16(Ap + 16 * K,  AsW + 512);
    gload16(Bp,           BsW);
    gload16(Bp + 16 * K,  BsW + 512);
    Ap += 32; Bp += 32;
    __syncthreads();                     // staging visible (vmcnt drained)

    s8v a[4], b[4];
#pragma unroll
    for (int i = 0; i < 4; ++i)
      a[i] = *(const s8v*)&As[(wr * 64 + i * 16 + l16) * 32 + quad * 8];
#pragma unroll
    for (int j = 0; j < 4; ++j)
      b[j] = *(const s8v*)&Bs[(wc * 64 + j * 16 + l16) * 32 + quad * 8];
#pragma unroll
    for (int i = 0; i < 4; ++i)
#pragma unroll
      for (int j = 0; j < 4; ++j)
        acc[i][j] = __builtin_amdgcn_mfma_f32_16x16x32_bf16(a[i], b[j], acc[i][j], 0, 0, 0);
  }

#pragma unroll
  for (int j = 0; j < 4; ++j) {
    int col = col0 + wc * 64 + j * 16 + l16;
    float bv = bias[col];
#pragma unroll
    for (int i = 0; i < 4; ++i) {
#pragma unroll
      for (int r = 0; r < 4; ++r) {
        int row = row0 + wr * 64 + i * 16 + quad * 4 + r;  // C/D: row=quad*4+reg
        float o = acc[i][j][r] + bv;
        if constexpr (std::is_same_v<OT, float>) C[(size_t)row * N + col] = o;
        else                                     C[(size_t)row * N + col] = f2b(o);
      }
    }
  }
}

// ---------------------------------------------------------------------------
// Fallback 64x64 GEMM (round-2 path, used only if workspace is too small)
// ---------------------------------------------------------------------------
template <typename AT, typename OT>
__global__ __launch_bounds__(256) void gemm_bias(
    const AT* __restrict__ A, const float* __restrict__ W,
    const float* __restrict__ bias, OT* __restrict__ C,
    int M, int N, int K)
{
  __shared__ __align__(16) unsigned short As[64][40];
  __shared__ __align__(16) unsigned short Bs[32][68];

  const int tid  = threadIdx.x;
  const int wave = tid >> 6;
  const int lane = tid & 63;
  const int l16  = lane & 15;
  const int quad = lane >> 4;
  const int row0 = blockIdx.y * 64;
  const int col0 = blockIdx.x * 64;

  f4v acc[4] = {};

  const int ar = tid >> 2;
  const int ac = (tid & 3) << 3;
  const int bk = tid >> 3;
  const int bn = (tid & 7) << 3;
  const AT*    Aptr = A + (size_t)(row0 + ar) * K + ac;
  const float* Wptr = W + (size_t)bk * N + col0 + bn;

  for (int k0 = 0; k0 < K; k0 += 32) {
    __syncthreads();
    if constexpr (std::is_same_v<AT, float>) {
      float4 a0 = *(const float4*)(Aptr);
      float4 a1 = *(const float4*)(Aptr + 4);
      s8v av;
      av[0] = (short)f2b(a0.x); av[1] = (short)f2b(a0.y);
      av[2] = (short)f2b(a0.z); av[3] = (short)f2b(a0.w);
      av[4] = (short)f2b(a1.x); av[5] = (short)f2b(a1.y);
      av[6] = (short)f2b(a1.z); av[7] = (short)f2b(a1.w);
      *(s8v*)&As[ar][ac] = av;
    } else {
      *(s8v*)&As[ar][ac] = *(const s8v*)(Aptr);
    }
    Aptr += 32;
    {
      float4 w0 = *(const float4*)(Wptr);
      float4 w1 = *(const float4*)(Wptr + 4);
      s4v b0, b1;
      b0[0] = (short)f2b(w0.x); b0[1] = (short)f2b(w0.y);
      b0[2] = (short)f2b(w0.z); b0[3] = (short)f2b(w0.w);
      b1[0] = (short)f2b(w1.x); b1[1] = (short)f2b(w1.y);
      b1[2] = (short)f2b(w1.z); b1[3] = (short)f2b(w1.w);
      *(s4v*)&Bs[bk][bn]     = b0;
      *(s4v*)&Bs[bk][bn + 4] = b1;
    }
    Wptr += (size_t)32 * N;
    __syncthreads();

    s8v a = *(const s8v*)&As[wave * 16 + l16][quad * 8];
#pragma unroll
    for (int nt = 0; nt < 4; ++nt) {
      s8v b;
#pragma unroll
      for (int j = 0; j < 8; ++j) b[j] = (short)Bs[quad * 8 + j][nt * 16 + l16];
      acc[nt] = __builtin_amdgcn_mfma_f32_16x16x32_bf16(a, b, acc[nt], 0, 0, 0);
    }
  }

#pragma unroll
  for (int nt = 0; nt < 4; ++nt) {
    int col = col0 + nt * 16 + l16;
    float bv = bias[col];
#pragma unroll
    for (int r = 0; r < 4; ++r) {
      int row = row0 + wave * 16 + quad * 4 + r;
      float o = acc[nt][r] + bv;
      if constexpr (std::is_same_v<OT, float>) C[(size_t)row * N + col] = o;
      else                                     C[(size_t)row * N + col] = f2b(o);
    }
  }
}

// ---------------------------------------------------------------------------
// RoPE (rotate-half) on q [T,32,128] and k [T,8,128] (bf16 bits) in place.
// ---------------------------------------------------------------------------
__global__ void rope_kernel(unsigned short* __restrict__ q,
                            unsigned short* __restrict__ k,
                            const int* __restrict__ pos, int T)
{
  const int t  = blockIdx.x;
  const int hh = blockIdx.y;              // 0..39
  const int d  = threadIdx.x;             // 0..63
  unsigned short* p = (hh < H_) ? q + ((size_t)t * D_ + hh * HD_)
                                : k + ((size_t)t * KVD_ + (hh - H_) * HD_);
  float pv   = (float)pos[t];
  float inv  = powf(1.0e6f, -(float)d * (1.0f / 64.0f));
  float fr   = pv * inv;
  float s, c;
  sincosf(fr, &s, &c);
  float x1 = b2f(p[d]), x2 = b2f(p[d + 64]);
  p[d]      = f2b(x1 * c - x2 * s);
  p[d + 64] = f2b(x2 * c + x1 * s);
}

// ---------------------------------------------------------------------------
// Block-sparse flash attention (bf16 in/out). One block per (head h, q-block).
// kv block kb active iff kb<=qb && (qb-kb<16 || (kb+h+1)%8==0).
// ---------------------------------------------------------------------------
__global__ __launch_bounds__(256) void attn_sparse(
    const unsigned short* __restrict__ Q, const unsigned short* __restrict__ K,
    const unsigned short* __restrict__ V, unsigned short* __restrict__ O, int T)
{
  __shared__ __align__(16) unsigned short Ks[64][136];   // [k][d], pad 8
  __shared__ __align__(16) unsigned short Vt[128][72];   // [d][k], pad 8
  __shared__ __align__(16) unsigned short Ps[4][16][72]; // per-wave P round-trip

  const int h   = blockIdx.x;
  const int qb  = blockIdx.y;
  const int hkv = h >> 2;                 // GQA: repeat each kv head 4x
  const int tid  = threadIdx.x;
  const int wave = tid >> 6;
  const int lane = tid & 63;
  const int l16  = lane & 15;
  const int quad = lane >> 4;

  const int qrow = qb * 64 + wave * 16 + l16;
  s8v qf[4];
#pragma unroll
  for (int s = 0; s < 4; ++s)
    qf[s] = *(const s8v*)(Q + (size_t)qrow * D_ + h * HD_ + s * 32 + quad * 8);

  float mrow[4] = {-1e30f, -1e30f, -1e30f, -1e30f};
  float lrow[4] = {0.f, 0.f, 0.f, 0.f};
  f4v oacc[8] = {};
  const int srow_base = qb * 64 + wave * 16 + quad * 4;

  for (int kb = 0; kb <= qb; ++kb) {
    if (!((qb - kb < 16) || (((kb + h + 1) & 7) == 0))) continue;

    __syncthreads();
#pragma unroll
    for (int i = 0; i < 4; ++i) {
      int seg = tid + 256 * i;
      int kr  = seg >> 4;
      int c   = (seg & 15) << 3;
      const size_t goff = (size_t)(kb * 64 + kr) * KVD_ + hkv * HD_ + c;
      *(s8v*)&Ks[kr][c] = *(const s8v*)(K + goff);
      s8v vv = *(const s8v*)(V + goff);
#pragma unroll
      for (int u = 0; u < 8; ++u) Vt[c + u][kr] = (unsigned short)vv[u];
    }
    __syncthreads();

    f4v sacc[4] = {};
#pragma unroll
    for (int kt = 0; kt < 4; ++kt) {
#pragma unroll
      for (int s = 0; s < 4; ++s) {
        s8v b = *(const s8v*)&Ks[kt * 16 + l16][s * 32 + quad * 8];
        sacc[kt] = __builtin_amdgcn_mfma_f32_16x16x32_bf16(qf[s], b, sacc[kt], 0, 0, 0);
      }
    }

    float p[4][4], rmax[4];
#pragma unroll
    for (int r = 0; r < 4; ++r) {
      float mx = -1e30f;
#pragma unroll
      for (int kt = 0; kt < 4; ++kt) {
        float sc = sacc[kt][r] * 0.08838834764831845f;
        int kcol = kb * 64 + kt * 16 + l16;
        if (kcol > srow_base + r) sc = -1e30f;
        p[r][kt] = sc;
        mx = fmaxf(mx, sc);
      }
#pragma unroll
      for (int off = 1; off < 16; off <<= 1)
        mx = fmaxf(mx, __shfl_xor(mx, off));
      rmax[r] = mx;
    }

    float alpha[4];
#pragma unroll
    for (int r = 0; r < 4; ++r) {
      float newm = fmaxf(mrow[r], rmax[r]);
      alpha[r] = __expf(mrow[r] - newm);
      mrow[r] = newm;
      float rs = 0.f;
#pragma unroll
      for (int kt = 0; kt < 4; ++kt) {
        unsigned short pb = f2b(__expf(p[r][kt] - newm));
        Ps[wave][quad * 4 + r][kt * 16 + l16] = pb;
        rs += b2f(pb);
      }
#pragma unroll
      for (int off = 1; off < 16; off <<= 1)
        rs += __shfl_xor(rs, off);
      lrow[r] = lrow[r] * alpha[r] + rs;
    }
#pragma unroll
    for (int dt = 0; dt < 8; ++dt) {
#pragma unroll
      for (int r = 0; r < 4; ++r) oacc[dt][r] *= alpha[r];
    }

    __syncthreads();

#pragma unroll
    for (int s2 = 0; s2 < 2; ++s2) {
      s8v af = *(const s8v*)&Ps[wave][l16][s2 * 32 + quad * 8];
#pragma unroll
      for (int dt = 0; dt < 8; ++dt) {
        s8v vf = *(const s8v*)&Vt[dt * 16 + l16][s2 * 32 + quad * 8];
        oacc[dt] = __builtin_amdgcn_mfma_f32_16x16x32_bf16(af, vf, oacc[dt], 0, 0, 0);
      }
    }
  }

#pragma unroll
  for (int r = 0; r < 4; ++r) {
    float inv = 1.0f / lrow[r];
    size_t rowoff = (size_t)(srow_base + r) * D_ + h * HD_;
#pragma unroll
    for (int dt = 0; dt < 8; ++dt)
      O[rowoff + dt * 16 + l16] = f2b(oacc[dt][r] * inv);
  }
}

// ---------------------------------------------------------------------------
extern "C" void kernel_launch(void* const* d_in, const int* in_sizes, int n_in,
                              void* d_out, int out_size, void* d_ws, size_t ws_size,
                              hipStream_t stream)
{
  const float* hs  = (const float*)d_in[0];
  const int*   pos = (const int*)d_in[1];
  const float* Wq  = (const float*)d_in[2];
  const float* bq  = (const float*)d_in[3];
  const float* Wk  = (const float*)d_in[4];
  const float* bk  = (const float*)d_in[5];
  const float* Wv  = (const float*)d_in[6];
  const float* bv  = (const float*)d_in[7];
  const float* Wo  = (const float*)d_in[8];
  const float* bo  = (const float*)d_in[9];
  float* out = (float*)d_out;

  const int T = in_sizes[1];   // 2048

  // bf16 workspace layout (element counts)
  const size_t nQ = (size_t)T * D_, nKV = (size_t)T * KVD_;
  unsigned short* qbuf = (unsigned short*)d_ws;
  unsigned short* kbuf = qbuf + nQ;
  unsigned short* vbuf = kbuf + nKV;
  unsigned short* abuf = vbuf + nKV;
  unsigned short* hsb  = abuf + nQ;                 // bf16 hidden states
  unsigned short* wtbuf= hsb  + nQ;                 // bf16 W^T staging (max 4096x4096)
  const size_t need = (size_t)(3 * nQ + 2 * nKV + nQ + (size_t)D_ * D_) * 2;

  dim3 blk(256);
  if (ws_size >= need) {
    // fp32 -> bf16 converts
    cvt_bf16<<<dim3((int)(nQ / 8 / 256)), blk, 0, stream>>>(hs, hsb, (int)(nQ / 8));
    // Q proj
    cvt_transpose<<<dim3(D_ / 64, D_ / 64), blk, 0, stream>>>(Wq, wtbuf, D_, D_);
    gemm_bt<unsigned short><<<dim3(D_ / 128, T / 128), blk, 0, stream>>>(
        hsb, wtbuf, bq, qbuf, T, D_, D_);
    // K proj
    cvt_transpose<<<dim3(KVD_ / 64, D_ / 64), blk, 0, stream>>>(Wk, wtbuf, D_, KVD_);
    gemm_bt<unsigned short><<<dim3(KVD_ / 128, T / 128), blk, 0, stream>>>(
        hsb, wtbuf, bk, kbuf, T, KVD_, D_);
    // V proj
    cvt_transpose<<<dim3(KVD_ / 64, D_ / 64), blk, 0, stream>>>(Wv, wtbuf, D_, KVD_);
    gemm_bt<unsigned short><<<dim3(KVD_ / 128, T / 128), blk, 0, stream>>>(
        hsb, wtbuf, bv, vbuf, T, KVD_, D_);
    // O-proj weight transpose can overlap rope/attn in issue order (same stream)
    cvt_transpose<<<dim3(D_ / 64, D_ / 64), blk, 0, stream>>>(Wo, wtbuf, D_, D_);

    rope_kernel<<<dim3(T, H_ + HKV_), dim3(64), 0, stream>>>(qbuf, kbuf, pos, T);
    attn_sparse<<<dim3(H_, T / 64), blk, 0, stream>>>(qbuf, kbuf, vbuf, abuf, T);

    gemm_bt<float><<<dim3(D_ / 128, T / 128), blk, 0, stream>>>(
        abuf, wtbuf, bo, out, T, D_, D_);
  } else {
    // fallback: round-2 path (41.9 MB workspace)
    gemm_bias<float, unsigned short>
        <<<dim3(D_ / 64,   T / 64), blk, 0, stream>>>(hs, Wq, bq, qbuf, T, D_,   D_);
    gemm_bias<float, unsigned short>
        <<<dim3(KVD_ / 64, T / 64), blk, 0, stream>>>(hs, Wk, bk, kbuf, T, KVD_, D_);
    gemm_bias<float, unsigned short>
        <<<dim3(KVD_ / 64, T / 64), blk, 0, stream>>>(hs, Wv, bv, vbuf, T, KVD_, D_);
    rope_kernel<<<dim3(T, H_ + HKV_), dim3(64), 0, stream>>>(qbuf, kbuf, pos, T);
    attn_sparse<<<dim3(H_, T / 64), blk, 0, stream>>>(qbuf, kbuf, vbuf, abuf, T);
    gemm_bias<unsigned short, float>
        <<<dim3(D_ / 64,   T / 64), blk, 0, stream>>>(abuf, Wo, bo, out, T, D_,   D_);
  }
}

// Round 4
// 703.040 us; speedup vs baseline: 1.6397x; 1.1477x over previous
//
#include <hip/hip_runtime.h>
#include <type_traits>

#define H_    32
#define HKV_  8
#define HD_   128
#define D_    4096   // H*HD
#define KVD_  1024   // HKV*HD

typedef __attribute__((ext_vector_type(8))) short s8v;   // 8 x bf16 bits (4 VGPRs)
typedef __attribute__((ext_vector_type(4))) short s4v;
typedef __attribute__((ext_vector_type(4))) float f4v;

__device__ __forceinline__ float b2f(unsigned short u) {
  union { unsigned int i; float f; } v; v.i = ((unsigned int)u) << 16; return v.f;
}
__device__ __forceinline__ unsigned short f2b(float f) {
  unsigned int u = __float_as_uint(f);
  u += 0x7fffu + ((u >> 16) & 1u);          // round-to-nearest-even
  return (unsigned short)(u >> 16);
}

// async global->LDS, 16B/lane; LDS dest = wave-uniform base, HW adds lane*16
__device__ __forceinline__ void gload16(const unsigned short* g, unsigned short* l) {
  __builtin_amdgcn_global_load_lds((const __attribute__((address_space(1))) void*)g,
                                   (__attribute__((address_space(3))) void*)l, 16, 0, 0);
}

// ---------------------------------------------------------------------------
// fp32 -> bf16 flat convert (8 elems/thread)
// ---------------------------------------------------------------------------
__global__ void cvt_bf16(const float* __restrict__ x, unsigned short* __restrict__ y,
                         int n8)
{
  int i = blockIdx.x * blockDim.x + threadIdx.x;
  if (i >= n8) return;
  const float4* xp = (const float4*)x + (size_t)i * 2;
  float4 a = xp[0], b = xp[1];
  s8v v;
  v[0] = (short)f2b(a.x); v[1] = (short)f2b(a.y);
  v[2] = (short)f2b(a.z); v[3] = (short)f2b(a.w);
  v[4] = (short)f2b(b.x); v[5] = (short)f2b(b.y);
  v[6] = (short)f2b(b.z); v[7] = (short)f2b(b.w);
  *(s8v*)(y + (size_t)i * 8) = v;
}

// ---------------------------------------------------------------------------
// W [K][N] fp32 -> Wt [N][K] bf16, 64x64 LDS-tiled transpose+convert
// ---------------------------------------------------------------------------
__global__ __launch_bounds__(256) void cvt_transpose(
    const float* __restrict__ W, unsigned short* __restrict__ Wt, int K, int N)
{
  __shared__ unsigned short tile[64][72];
  const int k0 = blockIdx.y * 64, n0 = blockIdx.x * 64;
  const int tid = threadIdx.x;
#pragma unroll
  for (int it = 0; it < 4; ++it) {
    int idx = tid + it * 256;
    int r = idx >> 4;
    int c = (idx & 15) << 2;
    float4 w = *(const float4*)(W + (size_t)(k0 + r) * N + n0 + c);
    tile[c + 0][r] = f2b(w.x); tile[c + 1][r] = f2b(w.y);
    tile[c + 2][r] = f2b(w.z); tile[c + 3][r] = f2b(w.w);
  }
  __syncthreads();
#pragma unroll
  for (int it = 0; it < 2; ++it) {
    int idx = tid + it * 256;
    int n = idx >> 3;
    int kk = (idx & 7) << 3;
    *(s8v*)(Wt + (size_t)(n0 + n) * K + k0 + kk) = *(const s8v*)&tile[n][kk];
  }
}

// ---------------------------------------------------------------------------
// m97-style GEMM: C[M][N] = A[M][K] @ Bt[N][K]^T + bias.  A,Bt bf16; bias fp32.
// BiasRow: bias indexed by row (for producing V^T) instead of col.
// ---------------------------------------------------------------------------
template <typename OT, bool BiasRow>
__global__ __launch_bounds__(256) void gemm_bt(
    const unsigned short* __restrict__ A, const unsigned short* __restrict__ Bt,
    const float* __restrict__ bias, OT* __restrict__ C, int M, int N, int K)
{
  __shared__ __align__(16) unsigned short As[128 * 32];
  __shared__ __align__(16) unsigned short Bs[128 * 32];

  const int tid  = threadIdx.x;
  const int wave = tid >> 6;
  const int lane = tid & 63;
  const int l16  = lane & 15;
  const int quad = lane >> 4;
  const int row0 = blockIdx.y * 128;
  const int col0 = blockIdx.x * 128;
  const int wr   = wave >> 1, wc = wave & 1;

  const int srow = lane >> 2;
  const int skk  = (lane & 3) << 3;
  const unsigned short* Ap = A  + (size_t)(row0 + wave * 32 + srow) * K + skk;
  const unsigned short* Bp = Bt + (size_t)(col0 + wave * 32 + srow) * K + skk;
  unsigned short* AsW = As + wave * 1024;
  unsigned short* BsW = Bs + wave * 1024;

  f4v acc[4][4] = {};

  for (int k0 = 0; k0 < K; k0 += 32) {
    __syncthreads();
    gload16(Ap,           AsW);
    gload16(Ap + 16 * K,  AsW + 512);
    gload16(Bp,           BsW);
    gload16(Bp + 16 * K,  BsW + 512);
    Ap += 32; Bp += 32;
    __syncthreads();

    s8v a[4], b[4];
#pragma unroll
    for (int i = 0; i < 4; ++i)
      a[i] = *(const s8v*)&As[(wr * 64 + i * 16 + l16) * 32 + quad * 8];
#pragma unroll
    for (int j = 0; j < 4; ++j)
      b[j] = *(const s8v*)&Bs[(wc * 64 + j * 16 + l16) * 32 + quad * 8];
#pragma unroll
    for (int i = 0; i < 4; ++i)
#pragma unroll
      for (int j = 0; j < 4; ++j)
        acc[i][j] = __builtin_amdgcn_mfma_f32_16x16x32_bf16(a[i], b[j], acc[i][j], 0, 0, 0);
  }

#pragma unroll
  for (int j = 0; j < 4; ++j) {
    int col = col0 + wc * 64 + j * 16 + l16;
    float bc = BiasRow ? 0.f : bias[col];
#pragma unroll
    for (int i = 0; i < 4; ++i) {
#pragma unroll
      for (int r = 0; r < 4; ++r) {
        int row = row0 + wr * 64 + i * 16 + quad * 4 + r;
        float o = acc[i][j][r] + (BiasRow ? bias[row] : bc);
        if constexpr (std::is_same_v<OT, float>) C[(size_t)row * N + col] = o;
        else                                     C[(size_t)row * N + col] = f2b(o);
      }
    }
  }
}

// ---------------------------------------------------------------------------
// RoPE (rotate-half) on q [T,32,128] and k [T,8,128] (bf16 bits) in place.
// q additionally pre-scaled by SCALE*log2(e) so attention runs in exp2-domain.
// ---------------------------------------------------------------------------
__global__ void rope_kernel(unsigned short* __restrict__ q,
                            unsigned short* __restrict__ k,
                            const int* __restrict__ pos, int T)
{
  const int t  = blockIdx.x;
  const int hh = blockIdx.y;              // 0..39
  const int d  = threadIdx.x;             // 0..63
  const bool isq = (hh < H_);
  unsigned short* p = isq ? q + ((size_t)t * D_ + hh * HD_)
                          : k + ((size_t)t * KVD_ + (hh - H_) * HD_);
  const float g = isq ? (0.08838834764831845f * 1.4426950408889634f) : 1.0f;
  float pv   = (float)pos[t];
  float inv  = powf(1.0e6f, -(float)d * (1.0f / 64.0f));
  float fr   = pv * inv;
  float s, c;
  sincosf(fr, &s, &c);
  float x1 = b2f(p[d]), x2 = b2f(p[d + 64]);
  p[d]      = f2b((x1 * c - x2 * s) * g);
  p[d + 64] = f2b((x2 * c + x1 * s) * g);
}

// ---------------------------------------------------------------------------
// Block-sparse flash attention. Q [T,H,HD] (pre-scaled), K [T,HKV,HD],
// Vt [KVD][T] (V transposed), O [T,H*HD]. One block per (head, q-block of 64).
// LDS: K panels Ks[4][64][32] (16KB) | Vt panels Vs[2][128][32] (16KB);
// P-roundtrip aliases Ks (K dead after S-MFMAs; barrier separates).
// ---------------------------------------------------------------------------
__global__ __launch_bounds__(256) void attn_sparse(
    const unsigned short* __restrict__ Q, const unsigned short* __restrict__ K,
    const unsigned short* __restrict__ Vt, unsigned short* __restrict__ O, int T)
{
  __shared__ __align__(16) unsigned short lds[16384];   // 32 KB total
  unsigned short* ldsK = lds;            // Ks(s,key,c)  = s*2048 + key*32 + c
  unsigned short* ldsV = lds + 8192;     // Vs(p,d,c)    = p*4096 + d*32 + c
  unsigned short* ldsP = lds;            // Ps(w,r,c)    = w*1152 + r*72 + c (alias)

  const int h    = blockIdx.x;
  const int qb   = (gridDim.y - 1) - blockIdx.y;   // heavy blocks first
  const int hkv  = h >> 2;
  const int tid  = threadIdx.x;
  const int wave = tid >> 6;
  const int lane = tid & 63;
  const int l16  = lane & 15;
  const int quad = lane >> 4;

  // Q A-fragments (q pre-scaled by SCALE*log2e in rope)
  const int qrow = qb * 64 + wave * 16 + l16;
  s8v qf[4];
#pragma unroll
  for (int s = 0; s < 4; ++s)
    qf[s] = *(const s8v*)(Q + (size_t)qrow * D_ + h * HD_ + s * 32 + quad * 8);

  // staging address components (lane-invariant parts)
  const int lr4 = lane >> 2;             // 0..15
  const int lc8 = (lane & 3) << 3;       // 0,8,16,24
  // K: key = kb*64 + wave*16 + lr4 ; d = t*32 + lc8
  const unsigned short* Kp0 = K + (size_t)(wave * 16 + lr4) * KVD_ + hkv * HD_ + lc8;
  unsigned short* Kd0 = ldsK + wave * 512 + 0;     // + t*2048
  // V: d = (wave*2 + (t>>1))*16 + lr4 ; key = kb*64 + (t&1)*32 + lc8
  const unsigned short* Vp0 = Vt + (size_t)(hkv * HD_ + wave * 32 + lr4) * T + lc8;
  unsigned short* Vd0 = ldsV + wave * 1024;        // + (t&1)*4096 + (t>>1)*512

  float mrow[4] = {-1e30f, -1e30f, -1e30f, -1e30f};
  float lrow[4] = {0.f, 0.f, 0.f, 0.f};
  f4v oacc[8] = {};
  const int rowinb = wave * 16 + quad * 4;         // C-layout row within block

  for (int kb = 0; kb <= qb; ++kb) {
    if (!((qb - kb < 16) || (((kb + h + 1) & 7) == 0))) continue;

    __syncthreads();                     // (A) prior PV reads of Vs/Ps done
    {
      const unsigned short* kp = Kp0 + (size_t)(kb * 64) * KVD_;
      const unsigned short* vp = Vp0 + kb * 64;
#pragma unroll
      for (int t = 0; t < 4; ++t)
        gload16(kp + t * 32, Kd0 + t * 2048);
#pragma unroll
      for (int t = 0; t < 4; ++t)
        gload16(vp + (size_t)((t >> 1) * 16) * T + (t & 1) * 32,
                Vd0 + (t & 1) * 4096 + (t >> 1) * 512);
    }
    __syncthreads();                     // (B) staging visible

    // S = Q K^T
    f4v sacc[4] = {};
#pragma unroll
    for (int kt = 0; kt < 4; ++kt) {
#pragma unroll
      for (int s = 0; s < 4; ++s) {
        s8v b = *(const s8v*)&ldsK[s * 2048 + (kt * 16 + l16) * 32 + quad * 8];
        sacc[kt] = __builtin_amdgcn_mfma_f32_16x16x32_bf16(qf[s], b, sacc[kt], 0, 0, 0);
      }
    }
    __syncthreads();                     // (C) all waves done reading Ks

    // online softmax (exp2 domain; scores already scaled)
    const bool diag = (kb == qb);
    float p[4][4];
#pragma unroll
    for (int r = 0; r < 4; ++r) {
      float mx = -1e30f;
#pragma unroll
      for (int kt = 0; kt < 4; ++kt) {
        float sc = sacc[kt][r];
        if (diag && (kt * 16 + l16 > rowinb + r)) sc = -1e30f;
        p[r][kt] = sc;
        mx = fmaxf(mx, sc);
      }
#pragma unroll
      for (int off = 1; off < 16; off <<= 1)
        mx = fmaxf(mx, __shfl_xor(mx, off));
      float newm = fmaxf(mrow[r], mx);
      float alpha = exp2f(mrow[r] - newm);
      mrow[r] = newm;
      float rs = 0.f;
#pragma unroll
      for (int kt = 0; kt < 4; ++kt) {
        unsigned short pb = f2b(exp2f(p[r][kt] - newm));
        ldsP[wave * 1152 + (quad * 4 + r) * 72 + kt * 16 + l16] = pb;
        rs += b2f(pb);
      }
#pragma unroll
      for (int off = 1; off < 16; off <<= 1)
        rs += __shfl_xor(rs, off);
      lrow[r] = lrow[r] * alpha + rs;
#pragma unroll
      for (int dt = 0; dt < 8; ++dt) oacc[dt][r] *= alpha;
    }

    // O += P @ V  (Ps is wave-private: same-wave ds ordering suffices)
#pragma unroll
    for (int s2 = 0; s2 < 2; ++s2) {
      s8v af = *(const s8v*)&ldsP[wave * 1152 + l16 * 72 + s2 * 32 + quad * 8];
#pragma unroll
      for (int dt = 0; dt < 8; ++dt) {
        s8v vf = *(const s8v*)&ldsV[s2 * 4096 + (dt * 16 + l16) * 32 + quad * 8];
        oacc[dt] = __builtin_amdgcn_mfma_f32_16x16x32_bf16(af, vf, oacc[dt], 0, 0, 0);
      }
    }
  }

  // epilogue
#pragma unroll
  for (int r = 0; r < 4; ++r) {
    float inv = 1.0f / lrow[r];
    size_t rowoff = (size_t)(qb * 64 + rowinb + r) * D_ + h * HD_;
#pragma unroll
    for (int dt = 0; dt < 8; ++dt)
      O[rowoff + dt * 16 + l16] = f2b(oacc[dt][r] * inv);
  }
}

// ---------------------------------------------------------------------------
extern "C" void kernel_launch(void* const* d_in, const int* in_sizes, int n_in,
                              void* d_out, int out_size, void* d_ws, size_t ws_size,
                              hipStream_t stream)
{
  const float* hs  = (const float*)d_in[0];
  const int*   pos = (const int*)d_in[1];
  const float* Wq  = (const float*)d_in[2];
  const float* bq  = (const float*)d_in[3];
  const float* Wk  = (const float*)d_in[4];
  const float* bk  = (const float*)d_in[5];
  const float* Wv  = (const float*)d_in[6];
  const float* bv  = (const float*)d_in[7];
  const float* Wo  = (const float*)d_in[8];
  const float* bo  = (const float*)d_in[9];
  float* out = (float*)d_out;

  const int T = in_sizes[1];   // 2048

  const size_t nQ = (size_t)T * D_, nKV = (size_t)T * KVD_;
  unsigned short* qbuf = (unsigned short*)d_ws;
  unsigned short* kbuf = qbuf + nQ;
  unsigned short* vbuf = kbuf + nKV;     // holds V^T [KVD][T]
  unsigned short* abuf = vbuf + nKV;
  unsigned short* hsb  = abuf + nQ;
  unsigned short* wtbuf= hsb  + nQ;

  dim3 blk(256);
  cvt_bf16<<<dim3((int)(nQ / 8 / 256)), blk, 0, stream>>>(hs, hsb, (int)(nQ / 8));

  // Q = hs @ Wq + bq
  cvt_transpose<<<dim3(D_ / 64, D_ / 64), blk, 0, stream>>>(Wq, wtbuf, D_, D_);
  gemm_bt<unsigned short, false><<<dim3(D_ / 128, T / 128), blk, 0, stream>>>(
      hsb, wtbuf, bq, qbuf, T, D_, D_);
  // K = hs @ Wk + bk
  cvt_transpose<<<dim3(KVD_ / 64, D_ / 64), blk, 0, stream>>>(Wk, wtbuf, D_, KVD_);
  gemm_bt<unsigned short, false><<<dim3(KVD_ / 128, T / 128), blk, 0, stream>>>(
      hsb, wtbuf, bk, kbuf, T, KVD_, D_);
  // V^T = Wv^T @ hs^T + bv (per-row)
  cvt_transpose<<<dim3(KVD_ / 64, D_ / 64), blk, 0, stream>>>(Wv, wtbuf, D_, KVD_);
  gemm_bt<unsigned short, true><<<dim3(T / 128, KVD_ / 128), blk, 0, stream>>>(
      wtbuf, hsb, bv, vbuf, KVD_, T, D_);
  // Wo^T (must finish V^T gemm first; same stream serializes)
  cvt_transpose<<<dim3(D_ / 64, D_ / 64), blk, 0, stream>>>(Wo, wtbuf, D_, D_);

  rope_kernel<<<dim3(T, H_ + HKV_), dim3(64), 0, stream>>>(qbuf, kbuf, pos, T);
  attn_sparse<<<dim3(H_, T / 64), blk, 0, stream>>>(qbuf, kbuf, vbuf, abuf, T);

  gemm_bt<float, false><<<dim3(D_ / 128, T / 128), blk, 0, stream>>>(
      abuf, wtbuf, bo, out, T, D_, D_);
}

// Round 5
// 549.654 us; speedup vs baseline: 2.0973x; 1.2791x over previous
//
#include <hip/hip_runtime.h>
#include <type_traits>

#define H_    32
#define HKV_  8
#define HD_   128
#define D_    4096   // H*HD
#define KVD_  1024   // HKV*HD
#define NQKV_ 6144   // D_ + 2*KVD_

typedef __attribute__((ext_vector_type(8))) short s8v;   // 8 x bf16 bits (4 VGPRs)
typedef __attribute__((ext_vector_type(4))) float f4v;

__device__ __forceinline__ float b2f(unsigned short u) {
  union { unsigned int i; float f; } v; v.i = ((unsigned int)u) << 16; return v.f;
}
__device__ __forceinline__ unsigned short f2b(float f) {
  unsigned int u = __float_as_uint(f);
  u += 0x7fffu + ((u >> 16) & 1u);          // round-to-nearest-even
  return (unsigned short)(u >> 16);
}

// async global->LDS, 16B/lane; LDS dest = wave-uniform base, HW adds lane*16
__device__ __forceinline__ void gload16(const unsigned short* g, unsigned short* l) {
  __builtin_amdgcn_global_load_lds((const __attribute__((address_space(1))) void*)g,
                                   (__attribute__((address_space(3))) void*)l, 16, 0, 0);
}

// ---------------------------------------------------------------------------
// fp32 -> bf16 flat convert (8 elems/thread)
// ---------------------------------------------------------------------------
__global__ void cvt_bf16(const float* __restrict__ x, unsigned short* __restrict__ y,
                         int n8)
{
  int i = blockIdx.x * blockDim.x + threadIdx.x;
  if (i >= n8) return;
  const float4* xp = (const float4*)x + (size_t)i * 2;
  float4 a = xp[0], b = xp[1];
  s8v v;
  v[0] = (short)f2b(a.x); v[1] = (short)f2b(a.y);
  v[2] = (short)f2b(a.z); v[3] = (short)f2b(a.w);
  v[4] = (short)f2b(b.x); v[5] = (short)f2b(b.y);
  v[6] = (short)f2b(b.z); v[7] = (short)f2b(b.w);
  *(s8v*)(y + (size_t)i * 8) = v;
}

// ---------------------------------------------------------------------------
// concat bq|bk|bv -> bqkv fp32 [6144]
// ---------------------------------------------------------------------------
__global__ void concat_bias(const float* __restrict__ bq, const float* __restrict__ bk,
                            const float* __restrict__ bv, float* __restrict__ o)
{
  int i = blockIdx.x * blockDim.x + threadIdx.x;   // < 6144
  float v = (i < D_) ? bq[i] : (i < D_ + KVD_) ? bk[i - D_] : bv[i - D_ - KVD_];
  o[i] = v;
}

// ---------------------------------------------------------------------------
// W [K][N] fp32 -> Wt [N][K] bf16, 64x64 LDS-tiled transpose+convert
// ---------------------------------------------------------------------------
__global__ __launch_bounds__(256) void cvt_transpose(
    const float* __restrict__ W, unsigned short* __restrict__ Wt, int K, int N)
{
  __shared__ unsigned short tile[64][72];
  const int k0 = blockIdx.y * 64, n0 = blockIdx.x * 64;
  const int tid = threadIdx.x;
#pragma unroll
  for (int it = 0; it < 4; ++it) {
    int idx = tid + it * 256;
    int r = idx >> 4;
    int c = (idx & 15) << 2;
    float4 w = *(const float4*)(W + (size_t)(k0 + r) * N + n0 + c);
    tile[c + 0][r] = f2b(w.x); tile[c + 1][r] = f2b(w.y);
    tile[c + 2][r] = f2b(w.z); tile[c + 3][r] = f2b(w.w);
  }
  __syncthreads();
#pragma unroll
  for (int it = 0; it < 2; ++it) {
    int idx = tid + it * 256;
    int n = idx >> 3;
    int kk = (idx & 7) << 3;
    *(s8v*)(Wt + (size_t)(n0 + n) * K + k0 + kk) = *(const s8v*)&tile[n][kk];
  }
}

// ---------------------------------------------------------------------------
// bf16 [T][*] column-slice -> transposed [n][T]. Src stride lds_, 64x64 tiles.
// ---------------------------------------------------------------------------
__global__ __launch_bounds__(256) void vtrans(
    const unsigned short* __restrict__ S, int lds_, unsigned short* __restrict__ Dst,
    int T)
{
  __shared__ unsigned short tile[64][72];
  const int v0 = blockIdx.x * 64, t0 = blockIdx.y * 64;
  const int tid = threadIdx.x;
#pragma unroll
  for (int it = 0; it < 2; ++it) {
    int idx = tid + it * 256;           // 0..511
    int tr = idx >> 3;                  // 0..63
    int vc = (idx & 7) << 3;            // 0..56
    s8v val = *(const s8v*)(S + (size_t)(t0 + tr) * lds_ + v0 + vc);
#pragma unroll
    for (int u = 0; u < 8; ++u) tile[vc + u][tr] = (unsigned short)val[u];
  }
  __syncthreads();
#pragma unroll
  for (int it = 0; it < 2; ++it) {
    int idx = tid + it * 256;
    int vr = idx >> 3;
    int tc = (idx & 7) << 3;
    *(s8v*)(Dst + (size_t)(v0 + vr) * T + t0 + tc) = *(const s8v*)&tile[vr][tc];
  }
}

// ---------------------------------------------------------------------------
// m97-style GEMM: C[M][N](ldc) = A[M][K] @ Bt[N][K]^T + bias.
// 128x128 tile, BK=32, 4 waves each 64x64.
// ---------------------------------------------------------------------------
template <typename OT>
__global__ __launch_bounds__(256) void gemm_bt(
    const unsigned short* __restrict__ A, const unsigned short* __restrict__ Bt,
    const float* __restrict__ bias, OT* __restrict__ C, int M, int N, int K, int ldc)
{
  __shared__ __align__(16) unsigned short As[128 * 32];
  __shared__ __align__(16) unsigned short Bs[128 * 32];

  const int tid  = threadIdx.x;
  const int wave = tid >> 6;
  const int lane = tid & 63;
  const int l16  = lane & 15;
  const int quad = lane >> 4;
  const int row0 = blockIdx.y * 128;
  const int col0 = blockIdx.x * 128;
  const int wr   = wave >> 1, wc = wave & 1;

  const int srow = lane >> 2;
  const int skk  = (lane & 3) << 3;
  const unsigned short* Ap = A  + (size_t)(row0 + wave * 32 + srow) * K + skk;
  const unsigned short* Bp = Bt + (size_t)(col0 + wave * 32 + srow) * K + skk;
  unsigned short* AsW = As + wave * 1024;
  unsigned short* BsW = Bs + wave * 1024;

  f4v acc[4][4] = {};

  for (int k0 = 0; k0 < K; k0 += 32) {
    __syncthreads();
    gload16(Ap,           AsW);
    gload16(Ap + 16 * K,  AsW + 512);
    gload16(Bp,           BsW);
    gload16(Bp + 16 * K,  BsW + 512);
    Ap += 32; Bp += 32;
    __syncthreads();

    s8v a[4], b[4];
#pragma unroll
    for (int i = 0; i < 4; ++i)
      a[i] = *(const s8v*)&As[(wr * 64 + i * 16 + l16) * 32 + quad * 8];
#pragma unroll
    for (int j = 0; j < 4; ++j)
      b[j] = *(const s8v*)&Bs[(wc * 64 + j * 16 + l16) * 32 + quad * 8];
#pragma unroll
    for (int i = 0; i < 4; ++i)
#pragma unroll
      for (int j = 0; j < 4; ++j)
        acc[i][j] = __builtin_amdgcn_mfma_f32_16x16x32_bf16(a[i], b[j], acc[i][j], 0, 0, 0);
  }

#pragma unroll
  for (int j = 0; j < 4; ++j) {
    int col = col0 + wc * 64 + j * 16 + l16;
    float bc = bias[col];
#pragma unroll
    for (int i = 0; i < 4; ++i) {
#pragma unroll
      for (int r = 0; r < 4; ++r) {
        int row = row0 + wr * 64 + i * 16 + quad * 4 + r;
        float o = acc[i][j][r] + bc;
        if constexpr (std::is_same_v<OT, float>) C[(size_t)row * ldc + col] = o;
        else                                     C[(size_t)row * ldc + col] = f2b(o);
      }
    }
  }
}

// ---------------------------------------------------------------------------
// 128x64-tile GEMM variant (2x blocks for grid-starved shapes). 4 waves 2x2,
// each 64 rows x 32 cols. C fp32.
// ---------------------------------------------------------------------------
__global__ __launch_bounds__(256) void gemm_bt2(
    const unsigned short* __restrict__ A, const unsigned short* __restrict__ Bt,
    const float* __restrict__ bias, float* __restrict__ C, int M, int N, int K)
{
  __shared__ __align__(16) unsigned short As[128 * 32];   // 8 KB
  __shared__ __align__(16) unsigned short Bs[64 * 32];    // 4 KB

  const int tid  = threadIdx.x;
  const int wave = tid >> 6;
  const int lane = tid & 63;
  const int l16  = lane & 15;
  const int quad = lane >> 4;
  const int row0 = blockIdx.y * 128;
  const int col0 = blockIdx.x * 64;
  const int wr   = wave >> 1, wc = wave & 1;

  const int srow = lane >> 2;
  const int skk  = (lane & 3) << 3;
  const unsigned short* Ap = A  + (size_t)(row0 + wave * 32 + srow) * K + skk;
  const unsigned short* Bp = Bt + (size_t)(col0 + wave * 16 + srow) * K + skk;
  unsigned short* AsW = As + wave * 1024;
  unsigned short* BsW = Bs + wave * 512;

  f4v acc[4][2] = {};

  for (int k0 = 0; k0 < K; k0 += 32) {
    __syncthreads();
    gload16(Ap,           AsW);
    gload16(Ap + 16 * K,  AsW + 512);
    gload16(Bp,           BsW);
    Ap += 32; Bp += 32;
    __syncthreads();

    s8v a[4], b[2];
#pragma unroll
    for (int i = 0; i < 4; ++i)
      a[i] = *(const s8v*)&As[(wr * 64 + i * 16 + l16) * 32 + quad * 8];
#pragma unroll
    for (int j = 0; j < 2; ++j)
      b[j] = *(const s8v*)&Bs[(wc * 32 + j * 16 + l16) * 32 + quad * 8];
#pragma unroll
    for (int i = 0; i < 4; ++i)
#pragma unroll
      for (int j = 0; j < 2; ++j)
        acc[i][j] = __builtin_amdgcn_mfma_f32_16x16x32_bf16(a[i], b[j], acc[i][j], 0, 0, 0);
  }

#pragma unroll
  for (int j = 0; j < 2; ++j) {
    int col = col0 + wc * 32 + j * 16 + l16;
    float bc = bias[col];
#pragma unroll
    for (int i = 0; i < 4; ++i) {
#pragma unroll
      for (int r = 0; r < 4; ++r) {
        int row = row0 + wr * 64 + i * 16 + quad * 4 + r;
        C[(size_t)row * N + col] = acc[i][j][r] + bc;
      }
    }
  }
}

// ---------------------------------------------------------------------------
// RoPE tables: ct/st [T][64] fp32
// ---------------------------------------------------------------------------
__global__ void sincos_tab(const int* __restrict__ pos, float* __restrict__ ct,
                           float* __restrict__ st)
{
  const int t = blockIdx.x, d = threadIdx.x;    // d < 64
  float inv = powf(1.0e6f, -(float)d * (1.0f / 64.0f));
  float fr  = (float)pos[t] * inv;
  float s, c;
  sincosf(fr, &s, &c);
  ct[t * 64 + d] = c;
  st[t * 64 + d] = s;
}

// ---------------------------------------------------------------------------
// RoPE apply on qkv [T][6144] (cols 0..5119 = 40 heads x 128). q heads
// (hh<32) pre-scaled by SCALE*log2(e) for exp2-domain softmax.
// ---------------------------------------------------------------------------
__global__ void rope_apply(unsigned short* __restrict__ qkv,
                           const float* __restrict__ ct, const float* __restrict__ st,
                           int T)
{
  const int t  = blockIdx.x;
  const int hh = blockIdx.y;              // 0..39
  const int d  = threadIdx.x;             // 0..63
  unsigned short* p = qkv + (size_t)t * NQKV_ + hh * HD_;
  const float g = (hh < H_) ? (0.08838834764831845f * 1.4426950408889634f) : 1.0f;
  float c = ct[t * 64 + d], s = st[t * 64 + d];
  float x1 = b2f(p[d]), x2 = b2f(p[d + 64]);
  p[d]      = f2b((x1 * c - x2 * s) * g);
  p[d + 64] = f2b((x2 * c + x1 * s) * g);
}

// ---------------------------------------------------------------------------
// Block-sparse flash attention. Q rows in qkv (stride ldq, col h*128),
// K rows in qkv (stride ldq, col 4096 + hkv*128), Vt [KVD][T], O [T][4096].
// ---------------------------------------------------------------------------
__global__ __launch_bounds__(256) void attn_sparse(
    const unsigned short* __restrict__ QKV, int ldq,
    const unsigned short* __restrict__ Vt, unsigned short* __restrict__ O, int T)
{
  __shared__ __align__(16) unsigned short lds[16384];   // 32 KB
  unsigned short* ldsK = lds;            // Ks(s,key,c) = s*2048 + key*32 + c
  unsigned short* ldsV = lds + 8192;     // Vs(p,d,c)   = p*4096 + d*32 + c
  unsigned short* ldsP = lds;            // Ps alias (K dead after S-MFMAs)

  const int h    = blockIdx.x;
  const int qb   = (gridDim.y - 1) - blockIdx.y;   // heavy blocks first
  const int hkv  = h >> 2;
  const int tid  = threadIdx.x;
  const int wave = tid >> 6;
  const int lane = tid & 63;
  const int l16  = lane & 15;
  const int quad = lane >> 4;

  const int qrow = qb * 64 + wave * 16 + l16;
  s8v qf[4];
#pragma unroll
  for (int s = 0; s < 4; ++s)
    qf[s] = *(const s8v*)(QKV + (size_t)qrow * ldq + h * HD_ + s * 32 + quad * 8);

  const int lr4 = lane >> 2;
  const int lc8 = (lane & 3) << 3;
  const unsigned short* Kp0 = QKV + (size_t)(wave * 16 + lr4) * ldq
                              + D_ + hkv * HD_ + lc8;
  unsigned short* Kd0 = ldsK + wave * 512;
  const unsigned short* Vp0 = Vt + (size_t)(hkv * HD_ + wave * 32 + lr4) * T + lc8;
  unsigned short* Vd0 = ldsV + wave * 1024;

  float mrow[4] = {-1e30f, -1e30f, -1e30f, -1e30f};
  float lrow[4] = {0.f, 0.f, 0.f, 0.f};
  f4v oacc[8] = {};
  const int rowinb = wave * 16 + quad * 4;

  for (int kb = 0; kb <= qb; ++kb) {
    if (!((qb - kb < 16) || (((kb + h + 1) & 7) == 0))) continue;

    __syncthreads();                     // prior PV reads done
    {
      const unsigned short* kp = Kp0 + (size_t)(kb * 64) * ldq;
      const unsigned short* vp = Vp0 + kb * 64;
#pragma unroll
      for (int t = 0; t < 4; ++t)
        gload16(kp + t * 32, Kd0 + t * 2048);
#pragma unroll
      for (int t = 0; t < 4; ++t)
        gload16(vp + (size_t)((t >> 1) * 16) * T + (t & 1) * 32,
                Vd0 + (t & 1) * 4096 + (t >> 1) * 512);
    }
    __syncthreads();                     // staging visible

    f4v sacc[4] = {};
#pragma unroll
    for (int kt = 0; kt < 4; ++kt) {
#pragma unroll
      for (int s = 0; s < 4; ++s) {
        s8v b = *(const s8v*)&ldsK[s * 2048 + (kt * 16 + l16) * 32 + quad * 8];
        sacc[kt] = __builtin_amdgcn_mfma_f32_16x16x32_bf16(qf[s], b, sacc[kt], 0, 0, 0);
      }
    }
    __syncthreads();                     // all waves done reading Ks

    const bool diag = (kb == qb);
    float p[4][4];
#pragma unroll
    for (int r = 0; r < 4; ++r) {
      float mx = -1e30f;
#pragma unroll
      for (int kt = 0; kt < 4; ++kt) {
        float sc = sacc[kt][r];
        if (diag && (kt * 16 + l16 > rowinb + r)) sc = -1e30f;
        p[r][kt] = sc;
        mx = fmaxf(mx, sc);
      }
#pragma unroll
      for (int off = 1; off < 16; off <<= 1)
        mx = fmaxf(mx, __shfl_xor(mx, off));
      float newm = fmaxf(mrow[r], mx);
      float alpha = exp2f(mrow[r] - newm);
      mrow[r] = newm;
      float rs = 0.f;
#pragma unroll
      for (int kt = 0; kt < 4; ++kt) {
        unsigned short pb = f2b(exp2f(p[r][kt] - newm));
        ldsP[wave * 1152 + (quad * 4 + r) * 72 + kt * 16 + l16] = pb;
        rs += b2f(pb);
      }
#pragma unroll
      for (int off = 1; off < 16; off <<= 1)
        rs += __shfl_xor(rs, off);
      lrow[r] = lrow[r] * alpha + rs;
#pragma unroll
      for (int dt = 0; dt < 8; ++dt) oacc[dt][r] *= alpha;
    }

#pragma unroll
    for (int s2 = 0; s2 < 2; ++s2) {
      s8v af = *(const s8v*)&ldsP[wave * 1152 + l16 * 72 + s2 * 32 + quad * 8];
#pragma unroll
      for (int dt = 0; dt < 8; ++dt) {
        s8v vf = *(const s8v*)&ldsV[s2 * 4096 + (dt * 16 + l16) * 32 + quad * 8];
        oacc[dt] = __builtin_amdgcn_mfma_f32_16x16x32_bf16(af, vf, oacc[dt], 0, 0, 0);
      }
    }
  }

#pragma unroll
  for (int r = 0; r < 4; ++r) {
    float inv = 1.0f / lrow[r];
    size_t rowoff = (size_t)(qb * 64 + rowinb + r) * D_ + h * HD_;
#pragma unroll
    for (int dt = 0; dt < 8; ++dt)
      O[rowoff + dt * 16 + l16] = f2b(oacc[dt][r] * inv);
  }
}

// ---------------------------------------------------------------------------
extern "C" void kernel_launch(void* const* d_in, const int* in_sizes, int n_in,
                              void* d_out, int out_size, void* d_ws, size_t ws_size,
                              hipStream_t stream)
{
  const float* hs  = (const float*)d_in[0];
  const int*   pos = (const int*)d_in[1];
  const float* Wq  = (const float*)d_in[2];
  const float* bq  = (const float*)d_in[3];
  const float* Wk  = (const float*)d_in[4];
  const float* bk  = (const float*)d_in[5];
  const float* Wv  = (const float*)d_in[6];
  const float* bv  = (const float*)d_in[7];
  const float* Wo  = (const float*)d_in[8];
  const float* bo  = (const float*)d_in[9];
  float* out = (float*)d_out;

  const int T = in_sizes[1];   // 2048

  // workspace layout (ushort elems), ~97.5 MB total:
  //  hsb [T*4096]     (aliases attn output abuf after QKV gemm)
  //  qkv [T*6144]
  //  vt  [1024*T]
  //  wbuf[6144*4096]  (WqkvT; later WoT)
  //  bqkv fp32[6144] | ct fp32[T*64] | st fp32[T*64]
  const size_t nQ = (size_t)T * D_;
  unsigned short* hsb  = (unsigned short*)d_ws;
  unsigned short* qkv  = hsb + nQ;
  unsigned short* vt   = qkv + (size_t)T * NQKV_;
  unsigned short* wbuf = vt  + (size_t)KVD_ * T;
  unsigned short* tail = wbuf + (size_t)NQKV_ * D_;
  float* bqkv = (float*)tail;
  float* ct   = bqkv + NQKV_;
  float* st   = ct + (size_t)T * 64;
  unsigned short* abuf = hsb;   // alias: attn output, read by O-proj

  dim3 blk(256);
  cvt_bf16<<<dim3((int)(nQ / 8 / 256)), blk, 0, stream>>>(hs, hsb, (int)(nQ / 8));
  concat_bias<<<dim3(NQKV_ / 256), blk, 0, stream>>>(bq, bk, bv, bqkv);
  sincos_tab<<<dim3(T), dim3(64), 0, stream>>>(pos, ct, st);

  // WqkvT: rows 0..4095 = WqT, 4096..5119 = WkT, 5120..6143 = WvT
  cvt_transpose<<<dim3(D_ / 64,   D_ / 64), blk, 0, stream>>>(Wq, wbuf, D_, D_);
  cvt_transpose<<<dim3(KVD_ / 64, D_ / 64), blk, 0, stream>>>(
      Wk, wbuf + (size_t)D_ * D_, D_, KVD_);
  cvt_transpose<<<dim3(KVD_ / 64, D_ / 64), blk, 0, stream>>>(
      Wv, wbuf + (size_t)(D_ + KVD_) * D_, D_, KVD_);

  // fused QKV projection: qkv[T][6144]
  gemm_bt<unsigned short><<<dim3(NQKV_ / 128, T / 128), blk, 0, stream>>>(
      hsb, wbuf, bqkv, qkv, T, NQKV_, D_, NQKV_);

  rope_apply<<<dim3(T, H_ + HKV_), dim3(64), 0, stream>>>(qkv, ct, st, T);
  vtrans<<<dim3(KVD_ / 64, T / 64), blk, 0, stream>>>(
      qkv + D_ + KVD_, NQKV_, vt, T);

  attn_sparse<<<dim3(H_, T / 64), blk, 0, stream>>>(qkv, NQKV_, vt, abuf, T);

  // O-proj (wbuf safe to overwrite after QKV gemm; stream serializes)
  cvt_transpose<<<dim3(D_ / 64, D_ / 64), blk, 0, stream>>>(Wo, wbuf, D_, D_);
  gemm_bt2<<<dim3(D_ / 64, T / 128), blk, 0, stream>>>(
      abuf, wbuf, bo, out, T, D_, D_);
}